// Round 10
// baseline (901.373 us; speedup 1.0000x reference)
//
#include <hip/hip_runtime.h>

#define K 8192
#define NROWS 8192
#define NSTEPS 100
#define QEPS 1.1920928955078125e-07f

// amdgpu_waves_per_eu(4,4): clamp BOTH ends of the waves/EU range.
// With a [4,8] range the backend's occupancy-driven rematerialization
// re-sinks the (invariant, restrict-const) global loads into the 100-step
// loop chasing 8 waves/EU (VGPR_Count=28; 25.6 TB of L2 re-reads at
// ~35.5 TB/s = L2 ceiling -> 720us). Clamping max=4 gives a 128-VGPR
// budget and removes the remat incentive.
__global__ __launch_bounds__(256)
__attribute__((amdgpu_waves_per_eu(4, 4)))
void mse_observer_kernel(const float* __restrict__ x, float* __restrict__ out)
{
    const int row  = blockIdx.x;
    const int tid  = threadIdx.x;
    const int lane = tid & 63;
    const int wave = tid >> 6;

    const float4* __restrict__ xr =
        reinterpret_cast<const float4*>(x + (size_t)row * K);

    // 32 elements/thread in 8 named float4s.
    float4 v0 = xr[tid +    0];
    float4 v1 = xr[tid +  256];
    float4 v2 = xr[tid +  512];
    float4 v3 = xr[tid +  768];
    float4 v4 = xr[tid + 1024];
    float4 v5 = xr[tid + 1280];
    float4 v6 = xr[tid + 1536];
    float4 v7 = xr[tid + 1792];

    // Pin each SCALAR component in a VGPR via empty inline asm (an aggregate
    // "+v"(float4) fails: "tied indirect register inputs" unsupported).
    // Inline asm defs are never rematerializable, so the loads cannot be
    // re-sunk into the loop. Safe at the 128-VGPR budget (no spill pressure).
#define PIN4(v) asm volatile("" : "+v"(v.x), "+v"(v.y), "+v"(v.z), "+v"(v.w))
    PIN4(v0); PIN4(v1); PIN4(v2); PIN4(v3);
    PIN4(v4); PIN4(v5); PIN4(v6); PIN4(v7);
#undef PIN4

    // Per-thread min/max
    float vmin = fminf(fminf(v0.x, v0.y), fminf(v0.z, v0.w));
    float vmax = fmaxf(fmaxf(v0.x, v0.y), fmaxf(v0.z, v0.w));
#define MM4(v) do { \
        vmin = fminf(vmin, fminf(fminf(v.x, v.y), fminf(v.z, v.w))); \
        vmax = fmaxf(vmax, fmaxf(fmaxf(v.x, v.y), fmaxf(v.z, v.w))); } while (0)
    MM4(v1); MM4(v2); MM4(v3); MM4(v4); MM4(v5); MM4(v6); MM4(v7);
#undef MM4

    // Wave (64-lane) reduce
    #pragma unroll
    for (int off = 32; off >= 1; off >>= 1) {
        vmin = fminf(vmin, __shfl_xor(vmin, off));
        vmax = fmaxf(vmax, __shfl_xor(vmax, off));
    }

    __shared__ float  smin[4], smax[4];
    __shared__ float2 sitab[NSTEPS];      // (s, 1/s) per step
    __shared__ float  partial[NSTEPS * 4];
    __shared__ float  sloss[NSTEPS];

    if (lane == 0) { smin[wave] = vmin; smax[wave] = vmax; }
    __syncthreads();

    const float rmin  = fminf(fminf(smin[0], smin[1]), fminf(smin[2], smin[3]));
    const float rmax  = fmaxf(fmaxf(smax[0], smax[1]), fmaxf(smax[2], smax[3]));
    const float range = fmaxf(fabsf(rmin), rmax);
    const float rstep = range / (float)NSTEPS;   // matches range_val / STEPS

    // Per-step scale table computed once (no per-step v_rcp in the hot loop).
    if (tid < NSTEPS) {
        const float thres = rstep * (float)(tid + 1);
        const float s     = fmaxf(thres / 127.5f, QEPS);
        sitab[tid] = make_float2(s, 1.0f / s);
    }
    __syncthreads();

    for (int i = 0; i < NSTEPS; ++i) {
        const float2 si   = sitab[i];     // broadcast ds_read_b64
        const float s     = si.x;
        const float inv_s = si.y;
        float acc0 = 0.0f, acc1 = 0.0f;   // 2 chains: hide FMA dep latency
#define QE(val, acc) do { \
        float q = __builtin_amdgcn_fmed3f( \
            __builtin_rintf((val) * inv_s), -128.0f, 127.0f); \
        float d = __builtin_fmaf(q, s, -(val)); \
        acc = __builtin_fmaf(d, d, acc); } while (0)
        QE(v0.x, acc0); QE(v0.y, acc1); QE(v0.z, acc0); QE(v0.w, acc1);
        QE(v1.x, acc0); QE(v1.y, acc1); QE(v1.z, acc0); QE(v1.w, acc1);
        QE(v2.x, acc0); QE(v2.y, acc1); QE(v2.z, acc0); QE(v2.w, acc1);
        QE(v3.x, acc0); QE(v3.y, acc1); QE(v3.z, acc0); QE(v3.w, acc1);
        QE(v4.x, acc0); QE(v4.y, acc1); QE(v4.z, acc0); QE(v4.w, acc1);
        QE(v5.x, acc0); QE(v5.y, acc1); QE(v5.z, acc0); QE(v5.w, acc1);
        QE(v6.x, acc0); QE(v6.y, acc1); QE(v6.z, acc0); QE(v6.w, acc1);
        QE(v7.x, acc0); QE(v7.y, acc1); QE(v7.z, acc0); QE(v7.w, acc1);
#undef QE
        float acc = acc0 + acc1;
        // Wave reduce sum
        #pragma unroll
        for (int off = 32; off >= 1; off >>= 1) acc += __shfl_xor(acc, off);
        if (lane == 0) partial[i * 4 + wave] = acc;   // own slot, no race
    }
    __syncthreads();

    // Combine wave partials (sum over row; mean = sum * 2^-13 exact, argmin same)
    if (tid < NSTEPS) {
        sloss[tid] = (partial[tid * 4 + 0] + partial[tid * 4 + 1]) +
                     (partial[tid * 4 + 2] + partial[tid * 4 + 3]);
    }
    __syncthreads();

    if (tid == 0) {
        float opt = 3.4e38f;
        int best = 0;
        #pragma unroll 1
        for (int i = 0; i < NSTEPS; ++i) {
            float l = sloss[i];
            if (l < opt) { opt = l; best = i; }   // strict <: earliest min
        }
        const float tbest = rstep * (float)(best + 1);
        out[row]         = -tbest;   // min_val
        out[NROWS + row] =  tbest;   // max_val
    }
}

extern "C" void kernel_launch(void* const* d_in, const int* in_sizes, int n_in,
                              void* d_out, int out_size, void* d_ws, size_t ws_size,
                              hipStream_t stream) {
    const float* x = (const float*)d_in[0];
    float* out = (float*)d_out;
    mse_observer_kernel<<<NROWS, 256, 0, stream>>>(x, out);
}